// Round 6
// baseline (248.897 us; speedup 1.0000x reference)
//
#include <hip/hip_runtime.h>
#include <stdint.h>

#define Mdim 4096
#define Kdim 4096
#define Ndim 4096

typedef __attribute__((ext_vector_type(4))) int v4i;
typedef __attribute__((ext_vector_type(16))) int v16i;

__device__ __forceinline__ void gload_lds16(const void* g, void* l) {
  __builtin_amdgcn_global_load_lds(
      (__attribute__((address_space(1))) void*)(uintptr_t)g,
      (__attribute__((address_space(3))) void*)(uint32_t)(uintptr_t)l,
      16, 0, 0);
}

__device__ __forceinline__ int bytesum_i8(int w, int acc) {
#if __has_builtin(__builtin_amdgcn_sdot4)
  return __builtin_amdgcn_sdot4(w, 0x01010101, acc, false);
#else
  return acc + (int)(char)(w) + (int)(char)(w >> 8) + (int)(char)(w >> 16) +
         (w >> 24);
#endif
}

__device__ __forceinline__ int pack4(int4 v) {
  return (v.x & 0xff) | ((v.y & 0xff) << 8) | ((v.z & 0xff) << 16) | (v.w << 24);
}

// ---- pack x (int32 [M][K] -> int8 [M][K]) + row sums -----------------------
__global__ __launch_bounds__(256) void pack_x_kernel(const int* __restrict__ x,
                                                     char* __restrict__ x8,
                                                     int* __restrict__ rsx) {
  const int row = blockIdx.x;
  const int t = threadIdx.x;
  const int4* src = (const int4*)(x + (size_t)row * Kdim);
  int* dst = (int*)(x8 + (size_t)row * Kdim);
  int sum = 0;
#pragma unroll
  for (int i = 0; i < 4; ++i) {
    int4 v = src[t + 256 * i];
    sum += v.x + v.y + v.z + v.w;
    dst[t + 256 * i] = pack4(v);
  }
#pragma unroll
  for (int o = 32; o > 0; o >>= 1) sum += __shfl_down(sum, o, 64);
  __shared__ int red[4];
  if ((t & 63) == 0) red[t >> 6] = sum;
  __syncthreads();
  if (t == 0) rsx[row] = red[0] + red[1] + red[2] + red[3];
}

// ---- pack + transpose y (int32 [K][N] -> int8 (y-128) [N][K]) + colsums ----
// Block = (n-tile of 64, k-eighth of 512), 8 inner 64x64 tiles.
// Per tile, thread (nq, kq) loads a 4(k)x4(n) int32 block as 4 int4,
// PACKS each k-row's 4 elements into a byte-word (bug fixed vs R5: previous
// version used only v.x), converts with XOR 0x80808080 (uint8 -> v-128 int8),
// 4x4-byte-transposes in register with 8 v_perm, writes 4 LDS words
// (n-row major, group-swizzled); phase 2 reads b128 and stores coalesced.
// Column sums accumulate in registers (sdot4) -> csp[8][4096], no atomics.
__global__ __launch_bounds__(256) void pack_yt_kernel(const int* __restrict__ y,
                                                      char* __restrict__ yt,
                                                      int* __restrict__ csp) {
  __shared__ int wt[64 * 20];  // row stride 20 words (80B, 16B-aligned)
  __shared__ int psum[4 * 64];
  const int t = threadIdx.x;
  const int n0 = blockIdx.x * 64;
  const int kbase = blockIdx.y * 512;
  const int w = t >> 6;
  const int u = t & 63;
  const int nq = u & 15;             // n-quad 0..15
  const int kq = w * 4 + (u >> 4);   // k-quad 0..15
  const int n_p2 = t >> 2;           // phase-2 n row
  const int g = t & 3;               // phase-2 16B group
  const int key1 = (nq >> 1) & 3;    // == ((4nq+i)>>3)&3 for i in 0..3
  const int key2 = (n_p2 >> 3) & 3;
  int csum[4] = {0, 0, 0, 0};

  for (int kt = 0; kt < 8; ++kt) {
    const int k0 = kbase + kt * 64;
    const int* srcp = y + (size_t)(k0 + kq * 4) * Ndim + n0 + nq * 4;
    int4 v0 = *(const int4*)(srcp);
    int4 v1 = *(const int4*)(srcp + Ndim);
    int4 v2 = *(const int4*)(srcp + 2 * Ndim);
    int4 v3 = *(const int4*)(srcp + 3 * Ndim);
    // pack 4 int32 elements (columns n) into bytes, then uint8 -> v-128 int8
    const int a0 = pack4(v0) ^ (int)0x80808080;
    const int a1 = pack4(v1) ^ (int)0x80808080;
    const int a2 = pack4(v2) ^ (int)0x80808080;
    const int a3 = pack4(v3) ^ (int)0x80808080;
    // 4x4 byte transpose: wo_i = [a0.b_i, a1.b_i, a2.b_i, a3.b_i] (k-packed)
    const unsigned x01l = __builtin_amdgcn_perm(a1, a0, 0x05010400u);
    const unsigned x01h = __builtin_amdgcn_perm(a1, a0, 0x07030602u);
    const unsigned x23l = __builtin_amdgcn_perm(a3, a2, 0x05010400u);
    const unsigned x23h = __builtin_amdgcn_perm(a3, a2, 0x07030602u);
    int wo[4];
    wo[0] = (int)__builtin_amdgcn_perm(x23l, x01l, 0x05040100u);
    wo[1] = (int)__builtin_amdgcn_perm(x23l, x01l, 0x07060302u);
    wo[2] = (int)__builtin_amdgcn_perm(x23h, x01h, 0x05040100u);
    wo[3] = (int)__builtin_amdgcn_perm(x23h, x01h, 0x07060302u);
#pragma unroll
    for (int i = 0; i < 4; ++i) {
      csum[i] = bytesum_i8(wo[i], csum[i]);
      const int n = nq * 4 + i;
      wt[n * 20 + (((kq >> 2) ^ key1) * 4) + (kq & 3)] = wo[i];
    }
    __syncthreads();
    v4i wv = *(const v4i*)(wt + n_p2 * 20 + (g ^ key2) * 4);
    *(v4i*)(yt + (size_t)(n0 + n_p2) * Kdim + k0 + g * 16) = wv;
    __syncthreads();
  }
  // reduce csum over kq: lanes u, u^16, u^32 share nq
#pragma unroll
  for (int i = 0; i < 4; ++i) {
    csum[i] += __shfl_xor(csum[i], 16, 64);
    csum[i] += __shfl_xor(csum[i], 32, 64);
  }
  if (u < 16) {
#pragma unroll
    for (int i = 0; i < 4; ++i) psum[w * 64 + u * 4 + i] = csum[i];
  }
  __syncthreads();
  if (t < 64) {
    const int tot = psum[t] + psum[64 + t] + psum[128 + t] + psum[192 + t];
    csp[blockIdx.y * Ndim + n0 + t] = tot;
  }
}

// ---- i8 GEMM: C = 7.5e-4*(A8 @ B8^T - 32*rsx[m] + 66*csy[n] - 2112*K) ------
// 256 thr / 4 waves, tile 256x128, BK=64, LDS 48KB -> two blocks/CU in
// independent barrier domains. Wave owns 64x128 as 2x4 MFMAs of 32x32x32_i8.
// Known plateau: ~37% of i8 µbench ceiling (structural to 2-barrier K-loop).
__global__ __launch_bounds__(256, 2) void gemm_i8_kernel(
    const char* __restrict__ A, const char* __restrict__ B,
    const int* __restrict__ rsx, const int* __restrict__ csp,
    float* __restrict__ out) {
  __shared__ __align__(16) char lds[2 * 24576];  // buf: [As 16K | Bs 8K]
  const int t = threadIdx.x;
  const int l = t & 63;
  const int w = t >> 6;
  const int bm = blockIdx.y * 256;
  const int bn = blockIdx.x * 128;

  v16i acc[2][4];
#pragma unroll
  for (int i = 0; i < 2; ++i)
#pragma unroll
    for (int j = 0; j < 4; ++j)
#pragma unroll
      for (int q = 0; q < 16; ++q) acc[i][j][q] = 0;

  const int srow = t >> 2;
  const int cswz = ((t & 3) ^ ((t >> 3) & 3)) * 16;
  const char* gA = A + (size_t)(bm + srow) * Kdim + cswz;
  const char* gB = B + (size_t)(bn + srow) * Kdim + cswz;

#define STAGE(buf_off, koff)                                                  \
  do {                                                                        \
    _Pragma("unroll") for (int i = 0; i < 4; ++i)                             \
        gload_lds16(gA + (koff) + (size_t)i * 64 * Kdim,                      \
                    lds + (buf_off) + i * 4096 + t * 16);                     \
    _Pragma("unroll") for (int i = 0; i < 2; ++i)                             \
        gload_lds16(gB + (koff) + (size_t)i * 64 * Kdim,                      \
                    lds + (buf_off) + 16384 + i * 4096 + t * 16);             \
  } while (0)

  const int arow = w * 64 + (l & 31);
  const int brow = l & 31;
  const int lhalf = l >> 5;
  const int lkey = (l >> 1) & 3;

#define COMPUTE_HALF(buf_off, ks)                                             \
  do {                                                                        \
    const char* As = lds + (buf_off);                                         \
    const char* Bs = lds + (buf_off) + 16384;                                 \
    const int slot = (((ks) * 2 + lhalf) ^ lkey) * 16;                        \
    v4i a[2], b[4];                                                           \
    _Pragma("unroll") for (int i = 0; i < 2; ++i)                             \
        a[i] = *(const v4i*)(As + (arow + i * 32) * 64 + slot);               \
    _Pragma("unroll") for (int j = 0; j < 4; ++j)                             \
        b[j] = *(const v4i*)(Bs + (brow + j * 32) * 64 + slot);               \
    _Pragma("unroll") for (int i = 0; i < 2; ++i)                             \
        _Pragma("unroll") for (int j = 0; j < 4; ++j)                         \
            acc[i][j] = __builtin_amdgcn_mfma_i32_32x32x32_i8(                \
                a[i], b[j], acc[i][j], 0, 0, 0);                              \
  } while (0)

  const int ksA = w & 1;

  STAGE(0, 0);
  __syncthreads();
  for (int kt = 0; kt < 64; kt += 2) {
    COMPUTE_HALF(0, ksA);
    STAGE(24576, (kt + 1) * 64);
    COMPUTE_HALF(0, ksA ^ 1);
    __syncthreads();
    COMPUTE_HALF(24576, ksA);
    if (kt + 2 < 64) STAGE(0, (kt + 2) * 64);
    COMPUTE_HALF(24576, ksA ^ 1);
    __syncthreads();
  }

  // Epilogue. C/D 32x32 layout: col=lane&31, row=(r&3)+8*(r>>2)+4*(lane>>5)
  const int col = l & 31;
  int csj[4];
#pragma unroll
  for (int j = 0; j < 4; ++j) {
    const int gn = bn + j * 32 + col;
    int s = 0;
#pragma unroll
    for (int p = 0; p < 8; ++p) s += csp[p * Ndim + gn];
    csj[j] = 66 * s - 8650752;  // -2112*4096
  }
#pragma unroll
  for (int i = 0; i < 2; ++i) {
    const int gm0 = bm + w * 64 + i * 32;
#pragma unroll
    for (int j = 0; j < 4; ++j) {
      const int gn = bn + j * 32 + col;
#pragma unroll
      for (int r = 0; r < 16; ++r) {
        const int row = (r & 3) + 8 * (r >> 2) + 4 * lhalf;
        const int gm = gm0 + row;
        const int val = acc[i][j][r] - 32 * rsx[gm] + csj[j];
        out[(size_t)gm * Ndim + gn] = 7.5e-4f * (float)val;
      }
    }
  }
#undef STAGE
#undef COMPUTE_HALF
}

extern "C" void kernel_launch(void* const* d_in, const int* in_sizes, int n_in,
                              void* d_out, int out_size, void* d_ws, size_t ws_size,
                              hipStream_t stream) {
  (void)in_sizes; (void)n_in; (void)out_size; (void)ws_size;
  const int* x = (const int*)d_in[0];
  const int* y = (const int*)d_in[1];
  float* out = (float*)d_out;
  char* ws = (char*)d_ws;
  char* x8 = ws;                                          // 16 MB
  char* yt = ws + (size_t)Mdim * Kdim;                    // 16 MB
  int* rsx = (int*)(ws + (size_t)Mdim * Kdim + (size_t)Kdim * Ndim);  // 16 KB
  int* csp = rsx + Mdim;                                  // 8*4096 ints

  pack_x_kernel<<<Mdim, 256, 0, stream>>>(x, x8, rsx);
  pack_yt_kernel<<<dim3(Ndim / 64, 8), 256, 0, stream>>>(y, yt, csp);
  gemm_i8_kernel<<<dim3(Ndim / 128, Mdim / 256), 256, 0, stream>>>(x8, yt, rsx, csp, out);
}